// Round 4
// baseline (161.519 us; speedup 1.0000x reference)
//
#include <hip/hip_runtime.h>

#define BB 16
#define CH 256
#define NH 4
#define DH 64
#define NN 1024

typedef _Float16 f16x8 __attribute__((ext_vector_type(8)));
typedef float f32x4 __attribute__((ext_vector_type(4)));

__device__ __forceinline__ unsigned short f2h(float x) {
    _Float16 h = (_Float16)x;
    return __builtin_bit_cast(unsigned short, h);
}

// ---------------- W -> fp16 hi/lo ----------------
__global__ __launch_bounds__(256) void prep_kernel(
    const float* __restrict__ Wq, const float* __restrict__ Wk, const float* __restrict__ Wv,
    unsigned short* __restrict__ Wh, unsigned short* __restrict__ Wl)
{
    int idx = blockIdx.x * 256 + threadIdx.x;   // 3*CH*CH = 196608
    if (idx >= 3 * CH * CH) return;
    int p = idx >> 16, oc = idx & 65535;
    const float* W = (p == 0) ? Wq : ((p == 1) ? Wk : Wv);
    float w = W[oc];
    _Float16 h = (_Float16)w;
    Wh[idx] = __builtin_bit_cast(unsigned short, h);
    Wl[idx] = f2h(w - (float)h);
}

// ---------------- x fp32 [b][c][n] -> xT fp16 [b][n][c] ----------------
__global__ __launch_bounds__(256) void xt_kernel(
    const float* __restrict__ x, unsigned short* __restrict__ xT)
{
    const int b = blockIdx.z, c0 = blockIdx.y * 32, n0 = blockIdx.x * 32;
    __shared__ float T[32][33];
    const int t = threadIdx.x;
    {
        int c = t >> 3, n4 = (t & 7) * 4;
        float4 v4 = *(const float4*)&x[((size_t)b * CH + c0 + c) * NN + n0 + n4];
        T[c][n4 + 0] = v4.x; T[c][n4 + 1] = v4.y;
        T[c][n4 + 2] = v4.z; T[c][n4 + 3] = v4.w;
    }
    __syncthreads();
    {
        int n = t >> 3, c4 = (t & 7) * 4;
        ushort4 o;
        o.x = f2h(T[c4 + 0][n]); o.y = f2h(T[c4 + 1][n]);
        o.z = f2h(T[c4 + 2][n]); o.w = f2h(T[c4 + 3][n]);
        *(ushort4*)&xT[((size_t)b * NN + n0 + n) * CH + c0 + c4] = o;
    }
}

// ---------------- pos^T fp16: pT[h][n][d] ----------------
__global__ __launch_bounds__(256) void pos_kernel(
    const float* __restrict__ rel_h, const float* __restrict__ rel_w,
    unsigned short* __restrict__ pT)
{
    int idx = blockIdx.x * 256 + threadIdx.x;     // NH*NN*DH = 262144
    if (idx >= NH * NN * DH) return;
    int d = idx & 63, n = (idx >> 6) & (NN - 1), h = idx >> 16;
    float val = rel_w[(h * DH + d) * 32 + (n >> 5)] + rel_h[(h * DH + d) * 32 + (n & 31)];
    pT[idx] = f2h(val);
}

// ---------------- projection via fp16 MFMA (W hi/lo 2-pass) ----------------
__global__ __launch_bounds__(256) void proj_kernel(
    const unsigned short* __restrict__ xT,
    const unsigned short* __restrict__ Wh, const unsigned short* __restrict__ Wl,
    const float* __restrict__ bq, const float* __restrict__ bk, const float* __restrict__ bv,
    unsigned short* __restrict__ qT, unsigned short* __restrict__ kT,
    unsigned short* __restrict__ vH)
{
    const int bz = blockIdx.z;
    const int b = bz / 3, p = bz % 3;
    const int n0 = blockIdx.x * 64;
    const int o0 = blockIdx.y * 64;
    const float* bias = (p == 0) ? bq : ((p == 1) ? bk : bv);

    __shared__ __align__(16) unsigned short Xs[64][72];
    __shared__ __align__(16) unsigned short Whs[64][72];
    __shared__ __align__(16) unsigned short Wls[64][72];

    const int tid = threadIdx.x;
    const int wid = tid >> 6, lane = tid & 63;
    const int g = lane >> 4, lr = lane & 15;

    const unsigned short* xb  = xT + (size_t)b * NN * CH;
    const unsigned short* Whp = Wh + (size_t)p * CH * CH;
    const unsigned short* Wlp = Wl + (size_t)p * CH * CH;

    const f32x4 z4 = {0.f, 0.f, 0.f, 0.f};
    f32x4 acc[4] = {z4, z4, z4, z4};

    for (int cs = 0; cs < 4; ++cs) {
        const int c0 = cs * 64;
        __syncthreads();
        #pragma unroll
        for (int rep = 0; rep < 2; ++rep) {
            int f = rep * 256 + tid;
            int r = f >> 3, s = f & 7;
            *(uint4*)&Xs[r][s * 8]  = *(const uint4*)&xb[(size_t)(n0 + r) * CH + c0 + s * 8];
            *(uint4*)&Whs[r][s * 8] = *(const uint4*)&Whp[(size_t)(o0 + r) * CH + c0 + s * 8];
            *(uint4*)&Wls[r][s * 8] = *(const uint4*)&Wlp[(size_t)(o0 + r) * CH + c0 + s * 8];
        }
        __syncthreads();
        #pragma unroll
        for (int ks = 0; ks < 2; ++ks) {
            f16x8 ah = *(const f16x8*)&Whs[wid * 16 + lr][ks * 32 + g * 8];
            f16x8 al = *(const f16x8*)&Wls[wid * 16 + lr][ks * 32 + g * 8];
            #pragma unroll
            for (int fc = 0; fc < 4; ++fc) {
                f16x8 bx = *(const f16x8*)&Xs[fc * 16 + lr][ks * 32 + g * 8];
                acc[fc] = __builtin_amdgcn_mfma_f32_16x16x32_f16(ah, bx, acc[fc], 0, 0, 0);
                acc[fc] = __builtin_amdgcn_mfma_f32_16x16x32_f16(al, bx, acc[fc], 0, 0, 0);
            }
        }
    }

    float bb[4];
    #pragma unroll
    for (int rr = 0; rr < 4; ++rr) bb[rr] = bias[o0 + wid * 16 + g * 4 + rr];

    if (p < 2) {
        const float scale = (p == 0) ? 1.44269504088896f : 1.0f;   // fold log2e into q
        __syncthreads();
        unsigned short (*Os)[72] = Whs;     // reuse as [n-local][o-local]
        #pragma unroll
        for (int fc = 0; fc < 4; ++fc)
            #pragma unroll
            for (int rr = 0; rr < 4; ++rr)
                Os[fc * 16 + lr][wid * 16 + g * 4 + rr] = f2h((acc[fc][rr] + bb[rr]) * scale);
        __syncthreads();
        unsigned short* dst = ((p == 0) ? qT : kT) + ((size_t)(b * NH + blockIdx.y) * NN + n0) * DH;
        #pragma unroll
        for (int rep = 0; rep < 2; ++rep) {
            int f = rep * 256 + tid;
            int r = f >> 3, s = f & 7;
            *(uint4*)&dst[(size_t)r * DH + s * 8] = *(const uint4*)&Os[r][s * 8];
        }
    } else {
        unsigned short* dv = vH + (size_t)b * CH * NN;
        #pragma unroll
        for (int fc = 0; fc < 4; ++fc)
            #pragma unroll
            for (int rr = 0; rr < 4; ++rr) {
                int o = o0 + wid * 16 + g * 4 + rr;
                dv[(size_t)o * NN + n0 + fc * 16 + lr] = f2h(acc[fc][rr] + bb[rr]);
            }
    }
}

// ---------------- fused flash attention, fp16 MFMA ----------------
// log2-domain energy: S = sum_{d<128} Qe[d][i]*Ke[d][j]; Qe=[q*log2e; pos], Ke=[k; q*log2e]
// defer-max (THR=8): fast path needs no cross-lane reduce at all.
// l via ones-MFMA: Lacc = mfma(aP, 1s, Lacc) -> row-sums, same rescale as Oacc.
// V read directly from global (L2-resident per (b,h), XCD-swizzled) -> no Vsh.
__global__ __launch_bounds__(256) void attn_kernel(
    const unsigned short* __restrict__ qT, const unsigned short* __restrict__ kT,
    const unsigned short* __restrict__ vH, const unsigned short* __restrict__ pT,
    float* __restrict__ out)
{
    const int wg = blockIdx.x;
    const int bh = (wg & 7) * 8 + ((wg >> 3) & 7);   // XCD-bijective: one (b,h) per XCD set
    const int it = wg >> 6;
    const int b = bh >> 2, h = bh & 3;
    const int i0 = it * 64;

    __shared__ __align__(16) unsigned short Ksh[64][136];   // Ke [j][d0..127], pad 8
    __shared__ __align__(16) unsigned short Ps[4][16][72];  // per-wave P [i][j]

    const int tid = threadIdx.x;
    const int wid = tid >> 6, lane = tid & 63;
    const int g = lane >> 4, lr = lane & 15;

    const size_t bhNN = (size_t)(b * NH + h) * NN;
    const unsigned short* qTb = qT + bhNN * DH;
    const unsigned short* kTb = kT + bhNN * DH;
    const unsigned short* pTb = pT + (size_t)h * NN * DH;
    const unsigned short* vb  = vH + ((size_t)b * CH + h * DH) * NN;

    // Q-ext A-fragments (registers, whole kernel)
    f16x8 aQ[4];
    {
        const int i = i0 + wid * 16 + lr;
        #pragma unroll
        for (int ks = 0; ks < 4; ++ks) {
            int d = ks * 32 + g * 8;
            const unsigned short* src = (d < 64) ? &qTb[(size_t)i * DH + d]
                                                 : &pTb[(size_t)i * DH + d - 64];
            aQ[ks] = *(const f16x8*)src;
        }
    }

    f16x8 vone;
    #pragma unroll
    for (int e = 0; e < 8; ++e) vone[e] = (_Float16)1.0f;

    // prefetch K-ext tile jt=0 into registers
    uint4 kst[4];
    #pragma unroll
    for (int rep = 0; rep < 4; ++rep) {
        int f = rep * 256 + tid;
        int r = f >> 4, s = f & 15;
        const unsigned short* src = (s < 8) ? &kTb[(size_t)r * DH + s * 8]
                                            : &qTb[(size_t)r * DH + (s - 8) * 8];
        kst[rep] = *(const uint4*)src;
    }

    const f32x4 z4 = {0.f, 0.f, 0.f, 0.f};
    f32x4 Oacc[4] = {z4, z4, z4, z4};
    f32x4 Lacc = z4;
    float m_run[4];
    #pragma unroll
    for (int r = 0; r < 4; ++r) m_run[r] = -1e30f;

    for (int jt = 0; jt < 16; ++jt) {
        const int jb = jt * 64;
        __syncthreads();    // previous tile's Ksh reads complete
        #pragma unroll
        for (int rep = 0; rep < 4; ++rep) {
            int f = rep * 256 + tid;
            int r = f >> 4, s = f & 15;
            *(uint4*)&Ksh[r][s * 8] = kst[rep];
        }
        __syncthreads();    // Ksh visible

        // issue next K tile + this tile's V fragments (hidden under QK+softmax)
        {
            const int jb2 = ((jt + 1) & 15) * 64;
            #pragma unroll
            for (int rep = 0; rep < 4; ++rep) {
                int f = rep * 256 + tid;
                int r = f >> 4, s = f & 15;
                const unsigned short* src = (s < 8) ? &kTb[(size_t)(jb2 + r) * DH + s * 8]
                                                    : &qTb[(size_t)(jb2 + r) * DH + (s - 8) * 8];
                kst[rep] = *(const uint4*)src;
            }
        }
        f16x8 vfr[2][4];
        #pragma unroll
        for (int ks = 0; ks < 2; ++ks)
            #pragma unroll
            for (int fc = 0; fc < 4; ++fc)
                vfr[ks][fc] = *(const f16x8*)&vb[(size_t)(fc * 16 + lr) * NN + jb + ks * 32 + g * 8];

        // ---- QK^T ----
        f32x4 S[4] = {z4, z4, z4, z4};
        __builtin_amdgcn_s_setprio(1);
        #pragma unroll
        for (int fc = 0; fc < 4; ++fc) {
            const int row = fc * 16 + lr;
            #pragma unroll
            for (int ks = 0; ks < 4; ++ks) {
                f16x8 bk8 = *(const f16x8*)&Ksh[row][ks * 32 + g * 8];
                S[fc] = __builtin_amdgcn_mfma_f32_16x16x32_f16(aQ[ks], bk8, S[fc], 0, 0, 0);
            }
        }
        __builtin_amdgcn_s_setprio(0);

        // ---- defer-max softmax (log2 domain) ----
        float fm[4], p[4][4];
        #pragma unroll
        for (int r = 0; r < 4; ++r)
            fm[r] = fmaxf(fmaxf(S[0][r], S[1][r]), fmaxf(S[2][r], S[3][r]));
        bool ok = (fm[0] <= m_run[0] + 8.f) && (fm[1] <= m_run[1] + 8.f) &&
                  (fm[2] <= m_run[2] + 8.f) && (fm[3] <= m_run[3] + 8.f);
        if (__all(ok)) {
            // fast path: no cross-lane reduce, no rescale; p <= 2^8 fits fp16
            #pragma unroll
            for (int r = 0; r < 4; ++r)
                #pragma unroll
                for (int fc = 0; fc < 4; ++fc)
                    p[fc][r] = exp2f(S[fc][r] - m_run[r]);
        } else {
            #pragma unroll
            for (int r = 0; r < 4; ++r) {
                float mt = fm[r];
                mt = fmaxf(mt, __shfl_xor(mt, 1));
                mt = fmaxf(mt, __shfl_xor(mt, 2));
                mt = fmaxf(mt, __shfl_xor(mt, 4));
                mt = fmaxf(mt, __shfl_xor(mt, 8));
                float mn = fmaxf(m_run[r], mt);
                float sc = exp2f(m_run[r] - mn);
                m_run[r] = mn;
                #pragma unroll
                for (int fc = 0; fc < 4; ++fc) {
                    Oacc[fc][r] *= sc;
                    p[fc][r] = exp2f(S[fc][r] - mn);
                }
                Lacc[r] *= sc;
            }
        }
        #pragma unroll
        for (int fc = 0; fc < 4; ++fc)
            #pragma unroll
            for (int r = 0; r < 4; ++r)
                Ps[wid][g * 4 + r][fc * 16 + lr] = f2h(p[fc][r]);

        // ---- PV + row-sum (wave-private Ps; no barrier) ----
        __builtin_amdgcn_s_setprio(1);
        #pragma unroll
        for (int ks = 0; ks < 2; ++ks) {
            f16x8 aP = *(const f16x8*)&Ps[wid][lr][ks * 32 + g * 8];
            Lacc = __builtin_amdgcn_mfma_f32_16x16x32_f16(aP, vone, Lacc, 0, 0, 0);
            #pragma unroll
            for (int fc = 0; fc < 4; ++fc)
                Oacc[fc] = __builtin_amdgcn_mfma_f32_16x16x32_f16(aP, vfr[ks][fc], Oacc[fc], 0, 0, 0);
        }
        __builtin_amdgcn_s_setprio(0);
    }

    // ---- epilogue: normalize by Lacc, LDS transpose (reuse Ksh), coalesced store ----
    __syncthreads();
    float inv[4];
    #pragma unroll
    for (int r = 0; r < 4; ++r) inv[r] = 1.0f / Lacc[r];
    float (*Os)[68] = (float (*)[68])(&Ksh[0][0]);
    #pragma unroll
    for (int fc = 0; fc < 4; ++fc)
        #pragma unroll
        for (int r = 0; r < 4; ++r)
            Os[fc * 16 + lr][wid * 16 + g * 4 + r] = Oacc[fc][r] * inv[r];
    __syncthreads();
    float* ob = out + ((size_t)b * CH + h * DH) * NN + i0;
    #pragma unroll
    for (int rep = 0; rep < 4; ++rep) {
        int f = rep * 256 + tid;
        int r = f >> 4, q4 = f & 15;
        *(float4*)&ob[(size_t)r * NN + q4 * 4] = *(const float4*)&Os[r][q4 * 4];
    }
}

extern "C" void kernel_launch(void* const* d_in, const int* in_sizes, int n_in,
                              void* d_out, int out_size, void* d_ws, size_t ws_size,
                              hipStream_t stream) {
    const float* x     = (const float*)d_in[0];
    const float* Wq    = (const float*)d_in[1];
    const float* bq    = (const float*)d_in[2];
    const float* Wk    = (const float*)d_in[3];
    const float* bk    = (const float*)d_in[4];
    const float* Wv    = (const float*)d_in[5];
    const float* bv    = (const float*)d_in[6];
    const float* rel_h = (const float*)d_in[7];
    const float* rel_w = (const float*)d_in[8];
    // d_in[9] (reg_qk), d_in[10] (reg_v): dead — reference discards the register-token group.
    float* out = (float*)d_out;

    const size_t SZ = (size_t)BB * NH * NN * DH;        // 4,194,304
    unsigned short* qT = (unsigned short*)d_ws;
    unsigned short* kT = qT + SZ;
    unsigned short* vH = kT + SZ;
    unsigned short* pT = vH + SZ;                       // NH*NN*DH = 262,144
    unsigned short* xT = pT + (size_t)NH * NN * DH;     // BB*NN*CH = 4,194,304
    unsigned short* Wh = xT + SZ;                       // 3*CH*CH = 196,608
    unsigned short* Wl = Wh + (size_t)3 * CH * CH;

    prep_kernel<<<dim3((3 * CH * CH + 255) / 256), 256, 0, stream>>>(Wq, Wk, Wv, Wh, Wl);
    xt_kernel<<<dim3(NN / 32, CH / 32, BB), 256, 0, stream>>>(x, xT);
    pos_kernel<<<dim3((NH * NN * DH + 255) / 256), 256, 0, stream>>>(rel_h, rel_w, pT);
    proj_kernel<<<dim3(NN / 64, CH / 64, BB * 3), 256, 0, stream>>>(
        xT, Wh, Wl, bq, bk, bv, qT, kT, vH);
    attn_kernel<<<dim3(1024), 256, 0, stream>>>(qT, kT, vH, pT, out);
}

// Round 5
// 156.901 us; speedup vs baseline: 1.0294x; 1.0294x over previous
//
#include <hip/hip_runtime.h>

#define BB 16
#define CH 256
#define NH 4
#define DH 64
#define NN 1024

typedef _Float16 f16x8 __attribute__((ext_vector_type(8)));
typedef float f32x4 __attribute__((ext_vector_type(4)));

__device__ __forceinline__ unsigned short f2h(float x) {
    _Float16 h = (_Float16)x;
    return __builtin_bit_cast(unsigned short, h);
}

// ---------------- W -> fp16 hi/lo ----------------
__global__ __launch_bounds__(256) void prep_kernel(
    const float* __restrict__ Wq, const float* __restrict__ Wk, const float* __restrict__ Wv,
    unsigned short* __restrict__ Wh, unsigned short* __restrict__ Wl)
{
    int idx = blockIdx.x * 256 + threadIdx.x;   // 3*CH*CH = 196608
    if (idx >= 3 * CH * CH) return;
    int p = idx >> 16, oc = idx & 65535;
    const float* W = (p == 0) ? Wq : ((p == 1) ? Wk : Wv);
    float w = W[oc];
    _Float16 h = (_Float16)w;
    Wh[idx] = __builtin_bit_cast(unsigned short, h);
    Wl[idx] = f2h(w - (float)h);
}

// ---------------- x fp32 [b][c][n] -> xT fp16 [b][n][c] ----------------
__global__ __launch_bounds__(256) void xt_kernel(
    const float* __restrict__ x, unsigned short* __restrict__ xT)
{
    const int b = blockIdx.z, c0 = blockIdx.y * 32, n0 = blockIdx.x * 32;
    __shared__ float T[32][33];
    const int t = threadIdx.x;
    {
        int c = t >> 3, n4 = (t & 7) * 4;
        float4 v4 = *(const float4*)&x[((size_t)b * CH + c0 + c) * NN + n0 + n4];
        T[c][n4 + 0] = v4.x; T[c][n4 + 1] = v4.y;
        T[c][n4 + 2] = v4.z; T[c][n4 + 3] = v4.w;
    }
    __syncthreads();
    {
        int n = t >> 3, c4 = (t & 7) * 4;
        ushort4 o;
        o.x = f2h(T[c4 + 0][n]); o.y = f2h(T[c4 + 1][n]);
        o.z = f2h(T[c4 + 2][n]); o.w = f2h(T[c4 + 3][n]);
        *(ushort4*)&xT[((size_t)b * NN + n0 + n) * CH + c0 + c4] = o;
    }
}

// ---------------- pos^T fp16: pT[h][n][d] ----------------
__global__ __launch_bounds__(256) void pos_kernel(
    const float* __restrict__ rel_h, const float* __restrict__ rel_w,
    unsigned short* __restrict__ pT)
{
    int idx = blockIdx.x * 256 + threadIdx.x;     // NH*NN*DH = 262144
    if (idx >= NH * NN * DH) return;
    int d = idx & 63, n = (idx >> 6) & (NN - 1), h = idx >> 16;
    float val = rel_w[(h * DH + d) * 32 + (n >> 5)] + rel_h[(h * DH + d) * 32 + (n & 31)];
    pT[idx] = f2h(val);
}

// ---------------- projection via fp16 MFMA (W hi/lo 2-pass) ----------------
__global__ __launch_bounds__(256) void proj_kernel(
    const unsigned short* __restrict__ xT,
    const unsigned short* __restrict__ Wh, const unsigned short* __restrict__ Wl,
    const float* __restrict__ bq, const float* __restrict__ bk, const float* __restrict__ bv,
    unsigned short* __restrict__ qT, unsigned short* __restrict__ kT,
    unsigned short* __restrict__ vH)
{
    const int bz = blockIdx.z;
    const int b = bz / 3, p = bz % 3;
    const int n0 = blockIdx.x * 64;
    const int o0 = blockIdx.y * 64;
    const float* bias = (p == 0) ? bq : ((p == 1) ? bk : bv);

    __shared__ __align__(16) unsigned short Xs[64][72];
    __shared__ __align__(16) unsigned short Whs[64][72];
    __shared__ __align__(16) unsigned short Wls[64][72];

    const int tid = threadIdx.x;
    const int wid = tid >> 6, lane = tid & 63;
    const int g = lane >> 4, lr = lane & 15;

    const unsigned short* xb  = xT + (size_t)b * NN * CH;
    const unsigned short* Whp = Wh + (size_t)p * CH * CH;
    const unsigned short* Wlp = Wl + (size_t)p * CH * CH;

    const f32x4 z4 = {0.f, 0.f, 0.f, 0.f};
    f32x4 acc[4] = {z4, z4, z4, z4};

    for (int cs = 0; cs < 4; ++cs) {
        const int c0 = cs * 64;
        __syncthreads();
        #pragma unroll
        for (int rep = 0; rep < 2; ++rep) {
            int f = rep * 256 + tid;
            int r = f >> 3, s = f & 7;
            *(uint4*)&Xs[r][s * 8]  = *(const uint4*)&xb[(size_t)(n0 + r) * CH + c0 + s * 8];
            *(uint4*)&Whs[r][s * 8] = *(const uint4*)&Whp[(size_t)(o0 + r) * CH + c0 + s * 8];
            *(uint4*)&Wls[r][s * 8] = *(const uint4*)&Wlp[(size_t)(o0 + r) * CH + c0 + s * 8];
        }
        __syncthreads();
        #pragma unroll
        for (int ks = 0; ks < 2; ++ks) {
            f16x8 ah = *(const f16x8*)&Whs[wid * 16 + lr][ks * 32 + g * 8];
            f16x8 al = *(const f16x8*)&Wls[wid * 16 + lr][ks * 32 + g * 8];
            #pragma unroll
            for (int fc = 0; fc < 4; ++fc) {
                f16x8 bx = *(const f16x8*)&Xs[fc * 16 + lr][ks * 32 + g * 8];
                acc[fc] = __builtin_amdgcn_mfma_f32_16x16x32_f16(ah, bx, acc[fc], 0, 0, 0);
                acc[fc] = __builtin_amdgcn_mfma_f32_16x16x32_f16(al, bx, acc[fc], 0, 0, 0);
            }
        }
    }

    float bb[4];
    #pragma unroll
    for (int rr = 0; rr < 4; ++rr) bb[rr] = bias[o0 + wid * 16 + g * 4 + rr];

    if (p < 2) {
        const float scale = (p == 0) ? 1.44269504088896f : 1.0f;   // fold log2e into q
        __syncthreads();
        unsigned short (*Os)[72] = Whs;     // reuse as [n-local][o-local]
        #pragma unroll
        for (int fc = 0; fc < 4; ++fc)
            #pragma unroll
            for (int rr = 0; rr < 4; ++rr)
                Os[fc * 16 + lr][wid * 16 + g * 4 + rr] = f2h((acc[fc][rr] + bb[rr]) * scale);
        __syncthreads();
        unsigned short* dst = ((p == 0) ? qT : kT) + ((size_t)(b * NH + blockIdx.y) * NN + n0) * DH;
        #pragma unroll
        for (int rep = 0; rep < 2; ++rep) {
            int f = rep * 256 + tid;
            int r = f >> 3, s = f & 7;
            *(uint4*)&dst[(size_t)r * DH + s * 8] = *(const uint4*)&Os[r][s * 8];
        }
    } else {
        unsigned short* dv = vH + (size_t)b * CH * NN;
        #pragma unroll
        for (int fc = 0; fc < 4; ++fc)
            #pragma unroll
            for (int rr = 0; rr < 4; ++rr) {
                int o = o0 + wid * 16 + g * 4 + rr;
                dv[(size_t)o * NN + n0 + fc * 16 + lr] = f2h(acc[fc][rr] + bb[rr]);
            }
    }
}

// ---------------- fused flash attention, fp16 MFMA ----------------
// log2-domain energy: S = sum_{d<128} Qe[d][i]*Ke[d][j]; Qe=[q*log2e; pos], Ke=[k; q*log2e]
// defer-max (THR=8 in log2 domain): fast path needs no cross-lane reduce.
// l via ones-MFMA. V staged in LDS (shared by 4 waves). Loads issued AFTER
// barrier-2 (syncthreads drains vmcnt — issuing before would serialize).
// __launch_bounds__(256,4): cap regs at 128/wave so 4 blocks/CU stay resident.
__global__ __launch_bounds__(256, 4) void attn_kernel(
    const unsigned short* __restrict__ qT, const unsigned short* __restrict__ kT,
    const unsigned short* __restrict__ vH, const unsigned short* __restrict__ pT,
    float* __restrict__ out)
{
    const int wg = blockIdx.x;
    const int bh = (wg & 7) * 8 + ((wg >> 3) & 7);   // XCD-bijective: one (b,h) per XCD set
    const int it = wg >> 6;
    const int b = bh >> 2, h = bh & 3;
    const int i0 = it * 64;

    __shared__ __align__(16) unsigned short Ksh[64][136];   // Ke [j][d0..127], pad 8
    __shared__ __align__(16) unsigned short Vsh[64][72];    // V  [d][j], pad 8
    __shared__ __align__(16) unsigned short Ps[4][16][72];  // per-wave P [i][j]

    const int tid = threadIdx.x;
    const int wid = tid >> 6, lane = tid & 63;
    const int g = lane >> 4, lr = lane & 15;

    const size_t bhNN = (size_t)(b * NH + h) * NN;
    const unsigned short* qTb = qT + bhNN * DH;
    const unsigned short* kTb = kT + bhNN * DH;
    const unsigned short* pTb = pT + (size_t)h * NN * DH;
    const unsigned short* vb  = vH + ((size_t)b * CH + h * DH) * NN;

    // Q-ext A-fragments (registers, whole kernel)
    f16x8 aQ[4];
    {
        const int i = i0 + wid * 16 + lr;
        #pragma unroll
        for (int ks = 0; ks < 4; ++ks) {
            int d = ks * 32 + g * 8;
            const unsigned short* src = (d < 64) ? &qTb[(size_t)i * DH + d]
                                                 : &pTb[(size_t)i * DH + d - 64];
            aQ[ks] = *(const f16x8*)src;
        }
    }

    f16x8 vone;
    #pragma unroll
    for (int e = 0; e < 8; ++e) vone[e] = (_Float16)1.0f;

    // prefetch K-ext + V tile jt=0 into registers
    uint4 kst[4], vst[2];
    #pragma unroll
    for (int rep = 0; rep < 4; ++rep) {
        int f = rep * 256 + tid;
        int r = f >> 4, s = f & 15;
        const unsigned short* src = (s < 8) ? &kTb[(size_t)r * DH + s * 8]
                                            : &qTb[(size_t)r * DH + (s - 8) * 8];
        kst[rep] = *(const uint4*)src;
    }
    #pragma unroll
    for (int rep = 0; rep < 2; ++rep) {
        int f = rep * 256 + tid;
        int d = f >> 3, j0 = (f & 7) * 8;
        vst[rep] = *(const uint4*)&vb[(size_t)d * NN + j0];
    }

    const f32x4 z4 = {0.f, 0.f, 0.f, 0.f};
    f32x4 Oacc[4] = {z4, z4, z4, z4};
    f32x4 Lacc = z4;
    float m_run[4];
    #pragma unroll
    for (int r = 0; r < 4; ++r) m_run[r] = -1e30f;

    for (int jt = 0; jt < 16; ++jt) {
        __syncthreads();    // previous tile's LDS reads complete
        #pragma unroll
        for (int rep = 0; rep < 4; ++rep) {
            int f = rep * 256 + tid;
            int r = f >> 4, s = f & 15;
            *(uint4*)&Ksh[r][s * 8] = kst[rep];
        }
        #pragma unroll
        for (int rep = 0; rep < 2; ++rep) {
            int f = rep * 256 + tid;
            int d = f >> 3, j0 = (f & 7) * 8;
            *(uint4*)&Vsh[d][j0] = vst[rep];
        }
        __syncthreads();    // LDS visible

        // issue next tile's loads now (after barrier: syncthreads drains vmcnt)
        {
            const int jb2 = ((jt + 1) & 15) * 64;
            #pragma unroll
            for (int rep = 0; rep < 4; ++rep) {
                int f = rep * 256 + tid;
                int r = f >> 4, s = f & 15;
                const unsigned short* src = (s < 8) ? &kTb[(size_t)(jb2 + r) * DH + s * 8]
                                                    : &qTb[(size_t)(jb2 + r) * DH + (s - 8) * 8];
                kst[rep] = *(const uint4*)src;
            }
            #pragma unroll
            for (int rep = 0; rep < 2; ++rep) {
                int f = rep * 256 + tid;
                int d = f >> 3, j0 = (f & 7) * 8;
                vst[rep] = *(const uint4*)&vb[(size_t)d * NN + jb2 + j0];
            }
        }

        // ---- QK^T ----
        f32x4 S[4] = {z4, z4, z4, z4};
        __builtin_amdgcn_s_setprio(1);
        #pragma unroll
        for (int fc = 0; fc < 4; ++fc) {
            const int row = fc * 16 + lr;
            #pragma unroll
            for (int ks = 0; ks < 4; ++ks) {
                f16x8 bk8 = *(const f16x8*)&Ksh[row][ks * 32 + g * 8];
                S[fc] = __builtin_amdgcn_mfma_f32_16x16x32_f16(aQ[ks], bk8, S[fc], 0, 0, 0);
            }
        }
        __builtin_amdgcn_s_setprio(0);

        // ---- defer-max softmax (log2 domain) ----
        float fm[4], p[4][4];
        #pragma unroll
        for (int r = 0; r < 4; ++r)
            fm[r] = fmaxf(fmaxf(S[0][r], S[1][r]), fmaxf(S[2][r], S[3][r]));
        bool ok = (fm[0] <= m_run[0] + 8.f) && (fm[1] <= m_run[1] + 8.f) &&
                  (fm[2] <= m_run[2] + 8.f) && (fm[3] <= m_run[3] + 8.f);
        if (__all(ok)) {
            // fast path: no cross-lane reduce, no rescale; p <= 2^8 fits fp16
            #pragma unroll
            for (int r = 0; r < 4; ++r)
                #pragma unroll
                for (int fc = 0; fc < 4; ++fc)
                    p[fc][r] = exp2f(S[fc][r] - m_run[r]);
        } else {
            #pragma unroll
            for (int r = 0; r < 4; ++r) {
                float mt = fm[r];
                mt = fmaxf(mt, __shfl_xor(mt, 1));
                mt = fmaxf(mt, __shfl_xor(mt, 2));
                mt = fmaxf(mt, __shfl_xor(mt, 4));
                mt = fmaxf(mt, __shfl_xor(mt, 8));
                float mn = fmaxf(m_run[r], mt);
                float sc = exp2f(m_run[r] - mn);
                m_run[r] = mn;
                #pragma unroll
                for (int fc = 0; fc < 4; ++fc) {
                    Oacc[fc][r] *= sc;
                    p[fc][r] = exp2f(S[fc][r] - mn);
                }
                Lacc[r] *= sc;
            }
        }
        #pragma unroll
        for (int fc = 0; fc < 4; ++fc)
            #pragma unroll
            for (int r = 0; r < 4; ++r)
                Ps[wid][g * 4 + r][fc * 16 + lr] = f2h(p[fc][r]);

        // ---- PV + row-sum (wave-private Ps; V from Vsh) ----
        __builtin_amdgcn_s_setprio(1);
        #pragma unroll
        for (int ks = 0; ks < 2; ++ks) {
            f16x8 aP = *(const f16x8*)&Ps[wid][lr][ks * 32 + g * 8];
            Lacc = __builtin_amdgcn_mfma_f32_16x16x32_f16(aP, vone, Lacc, 0, 0, 0);
            #pragma unroll
            for (int fc = 0; fc < 4; ++fc) {
                f16x8 bV = *(const f16x8*)&Vsh[fc * 16 + lr][ks * 32 + g * 8];
                Oacc[fc] = __builtin_amdgcn_mfma_f32_16x16x32_f16(aP, bV, Oacc[fc], 0, 0, 0);
            }
        }
        __builtin_amdgcn_s_setprio(0);
    }

    // ---- epilogue: normalize by Lacc, LDS transpose (reuse Ksh), coalesced store ----
    __syncthreads();
    float inv[4];
    #pragma unroll
    for (int r = 0; r < 4; ++r) inv[r] = 1.0f / Lacc[r];
    float (*Os)[68] = (float (*)[68])(&Ksh[0][0]);
    #pragma unroll
    for (int fc = 0; fc < 4; ++fc)
        #pragma unroll
        for (int r = 0; r < 4; ++r)
            Os[fc * 16 + lr][wid * 16 + g * 4 + r] = Oacc[fc][r] * inv[r];
    __syncthreads();
    float* ob = out + ((size_t)b * CH + h * DH) * NN + i0;
    #pragma unroll
    for (int rep = 0; rep < 4; ++rep) {
        int f = rep * 256 + tid;
        int r = f >> 4, q4 = f & 15;
        *(float4*)&ob[(size_t)r * NN + q4 * 4] = *(const float4*)&Os[r][q4 * 4];
    }
}

extern "C" void kernel_launch(void* const* d_in, const int* in_sizes, int n_in,
                              void* d_out, int out_size, void* d_ws, size_t ws_size,
                              hipStream_t stream) {
    const float* x     = (const float*)d_in[0];
    const float* Wq    = (const float*)d_in[1];
    const float* bq    = (const float*)d_in[2];
    const float* Wk    = (const float*)d_in[3];
    const float* bk    = (const float*)d_in[4];
    const float* Wv    = (const float*)d_in[5];
    const float* bv    = (const float*)d_in[6];
    const float* rel_h = (const float*)d_in[7];
    const float* rel_w = (const float*)d_in[8];
    // d_in[9] (reg_qk), d_in[10] (reg_v): dead — reference discards the register-token group.
    float* out = (float*)d_out;

    const size_t SZ = (size_t)BB * NH * NN * DH;        // 4,194,304
    unsigned short* qT = (unsigned short*)d_ws;
    unsigned short* kT = qT + SZ;
    unsigned short* vH = kT + SZ;
    unsigned short* pT = vH + SZ;                       // NH*NN*DH = 262,144
    unsigned short* xT = pT + (size_t)NH * NN * DH;     // BB*NN*CH = 4,194,304
    unsigned short* Wh = xT + SZ;                       // 3*CH*CH = 196,608
    unsigned short* Wl = Wh + (size_t)3 * CH * CH;

    prep_kernel<<<dim3((3 * CH * CH + 255) / 256), 256, 0, stream>>>(Wq, Wk, Wv, Wh, Wl);
    xt_kernel<<<dim3(NN / 32, CH / 32, BB), 256, 0, stream>>>(x, xT);
    pos_kernel<<<dim3((NH * NN * DH + 255) / 256), 256, 0, stream>>>(rel_h, rel_w, pT);
    proj_kernel<<<dim3(NN / 64, CH / 64, BB * 3), 256, 0, stream>>>(
        xT, Wh, Wl, bq, bk, bv, qT, kT, vH);
    attn_kernel<<<dim3(1024), 256, 0, stream>>>(qT, kT, vH, pT, out);
}